// Round 1
// baseline (273.344 us; speedup 1.0000x reference)
//
#include <hip/hip_runtime.h>

#define NCOL 1116
#define NLEV 7
#define NT 256
#define RPB 4        // rows per block, one wave each
#define ARENA 2048   // floats of LDS per row (8 KB)

static __device__ __forceinline__ float softf(float c, float t) {
    float m = fabsf(c) - t;
    return m > 0.0f ? copysignf(m, c) : 0.0f;
}

__global__ __launch_bounds__(NT)
void wavelet_kernel(const float* __restrict__ x,
                    const float* __restrict__ thr_ptr,
                    float* __restrict__ out, int nrow) {
    constexpr float DEC_LO[8] = {-0.010597401784997278f,  0.032883011666982945f,
                                  0.030841381835986965f, -0.18703481171888114f,
                                 -0.02798376941698385f,   0.6308807679295904f,
                                  0.7148465705525415f,    0.23037781330885523f};
    constexpr float DEC_HI[8] = {-0.23037781330885523f,   0.7148465705525415f,
                                 -0.6308807679295904f,   -0.02798376941698385f,
                                  0.18703481171888114f,   0.030841381835986965f,
                                 -0.032883011666982945f, -0.010597401784997278f};
    constexpr float REC_LO[8] = { 0.23037781330885523f,   0.7148465705525415f,
                                  0.6308807679295904f,   -0.02798376941698385f,
                                 -0.18703481171888114f,   0.030841381835986965f,
                                  0.032883011666982945f, -0.010597401784997278f};
    constexpr float REC_HI[8] = {-0.010597401784997278f, -0.032883011666982945f,
                                  0.030841381835986965f,  0.18703481171888114f,
                                 -0.02798376941698385f,  -0.6308807679295904f,
                                  0.7148465705525415f,   -0.23037781330885523f};

    // approx lengths per level
    constexpr int alen[8] = {1116, 561, 284, 145, 76, 41, 24, 15};
    // detail segment offsets, arena-relative (all even => 8B-aligned data):
    // d0..d4 overwrite the dead a0 buffer; d5,d6 in the tail.
    constexpr int doff[7] = {8, 570, 854, 1000, 1076, 2008, 2032};

    __shared__ __align__(16) float SH[RPB * ARENA];

    const int lane = threadIdx.x & 63;
    const int wv   = threadIdx.x >> 6;
    const int row  = blockIdx.x * RPB + wv;
    if (row >= nrow) return;   // no barriers in kernel -> early return is safe

    const float thr = fmaxf(thr_ptr[0], 0.01f);

    float* const arena = SH + wv * ARENA;
    float* const a8 = arena + 8;      // a0 data [8,1124) ; later d0..d4
    float* const b8 = arena + 1140;   // ping buffer, region [1132,1710)
    float* const c8 = arena + 1716;   // pong buffer, region [1710,2008)

    // ---- load row (1116*4B = 279 float4, 16B aligned) ----
    {
        const float4* xr = (const float4*)(x + (size_t)row * NCOL);
        float4* dst = (float4*)a8;
        for (int i = lane; i < NCOL / 4; i += 64) dst[i] = xr[i];
        // zero pads: front a8[-6..-1], back a8[1116..1123]
        if (lane < 14) { int j = lane < 6 ? lane - 6 : 1110 + lane; a8[j] = 0.0f; }
    }
    __builtin_amdgcn_wave_barrier();

    // ---- forward DWT, 7 levels, no block barriers (wave-private row) ----
    {
        float* cur = a8;
        float* nxt = b8;
        #pragma unroll
        for (int l = 0; l < NLEV; ++l) {
            const int nout = alen[l + 1];
            float* dp = arena + doff[l];
            for (int b = lane; 2 * b < nout; b += 64) {
                const int o = 2 * b;
                // window v[j] = cur[2o-6+j], j=0..9 covers outputs o and o+1
                const float* src = cur + o + o - 6;
                float v[10];
                #pragma unroll
                for (int j = 0; j < 10; ++j) v[j] = src[j];
                float lo0 = 0.f, hi0 = 0.f, lo1 = 0.f, hi1 = 0.f;
                #pragma unroll
                for (int s = 0; s < 8; ++s) {
                    lo0 = fmaf(DEC_LO[s], v[7 - s], lo0);
                    hi0 = fmaf(DEC_HI[s], v[7 - s], hi0);
                    lo1 = fmaf(DEC_LO[s], v[9 - s], lo1);
                    hi1 = fmaf(DEC_HI[s], v[9 - s], hi1);
                }
                float av0 = (l == NLEV - 1) ? softf(lo0, thr) : lo0;  // a7 threshold fused
                float dv0 = softf(hi0, thr);
                if (o + 1 < nout) {
                    float av1 = (l == NLEV - 1) ? softf(lo1, thr) : lo1;
                    *(float2*)(nxt + o) = make_float2(av0, av1);
                    *(float2*)(dp + o)  = make_float2(dv0, softf(hi1, thr));
                } else {
                    nxt[o] = av0;
                    dp[o]  = dv0;
                }
            }
            if (l < NLEV - 1) {
                // zero pads of nxt: front 6, back 9 (reads reach 2*nout_next+1)
                if (lane < 15) {
                    int j = lane < 6 ? lane - 6 : nout + lane - 6;
                    nxt[j] = 0.0f;
                }
            }
            __builtin_amdgcn_wave_barrier();
            if (l == 0) { cur = b8; nxt = c8; }           // A -> B, then B<->C
            else       { float* t = cur; cur = nxt; nxt = t; }
        }
    }

    // ---- inverse DWT ----
    {
        float* cur = b8;   // a7 lives in B after 7 forward levels
        float* nxt = c8;
        #pragma unroll
        for (int l = NLEV - 1; l >= 1; --l) {
            const int M = alen[l + 1];
            const float* dp = arena + doff[l];
            const int npair = M - 3;
            for (int b = lane; 2 * b < npair; b += 64) {
                const int m = 2 * b;
                float ca[5], cd[5];
                #pragma unroll
                for (int j = 0; j < 5; ++j) { ca[j] = cur[m + j]; cd[j] = dp[m + j]; }
                float y0 = fmaf(REC_LO[0], ca[3], fmaf(REC_LO[2], ca[2], fmaf(REC_LO[4], ca[1], REC_LO[6] * ca[0])));
                y0 = fmaf(REC_HI[0], cd[3], fmaf(REC_HI[2], cd[2], fmaf(REC_HI[4], cd[1], fmaf(REC_HI[6], cd[0], y0))));
                float y1 = fmaf(REC_LO[1], ca[3], fmaf(REC_LO[3], ca[2], fmaf(REC_LO[5], ca[1], REC_LO[7] * ca[0])));
                y1 = fmaf(REC_HI[1], cd[3], fmaf(REC_HI[3], cd[2], fmaf(REC_HI[5], cd[1], fmaf(REC_HI[7], cd[0], y1))));
                if (m + 1 < npair) {
                    float y2 = fmaf(REC_LO[0], ca[4], fmaf(REC_LO[2], ca[3], fmaf(REC_LO[4], ca[2], REC_LO[6] * ca[1])));
                    y2 = fmaf(REC_HI[0], cd[4], fmaf(REC_HI[2], cd[3], fmaf(REC_HI[4], cd[2], fmaf(REC_HI[6], cd[1], y2))));
                    float y3 = fmaf(REC_LO[1], ca[4], fmaf(REC_LO[3], ca[3], fmaf(REC_LO[5], ca[2], REC_LO[7] * ca[1])));
                    y3 = fmaf(REC_HI[1], cd[4], fmaf(REC_HI[3], cd[3], fmaf(REC_HI[5], cd[2], fmaf(REC_HI[7], cd[1], y3))));
                    *(float4*)(nxt + 2 * m) = make_float4(y0, y1, y2, y3);  // 16B aligned
                } else {
                    nxt[2 * m]     = y0;
                    nxt[2 * m + 1] = y1;
                }
            }
            __builtin_amdgcn_wave_barrier();
            float* t = cur; cur = nxt; nxt = t;
        }
        // final level: d0 from A, write straight to global as float4
        {
            const float* dp = arena + doff[0];
            float4* orow = (float4*)(out + (size_t)row * NCOL);
            const int npair = alen[1] - 3;   // 558 (even -> all full quads)
            for (int b = lane; 2 * b < npair; b += 64) {
                const int m = 2 * b;
                float ca[5], cd[5];
                #pragma unroll
                for (int j = 0; j < 5; ++j) { ca[j] = cur[m + j]; cd[j] = dp[m + j]; }
                float y0 = fmaf(REC_LO[0], ca[3], fmaf(REC_LO[2], ca[2], fmaf(REC_LO[4], ca[1], REC_LO[6] * ca[0])));
                y0 = fmaf(REC_HI[0], cd[3], fmaf(REC_HI[2], cd[2], fmaf(REC_HI[4], cd[1], fmaf(REC_HI[6], cd[0], y0))));
                float y1 = fmaf(REC_LO[1], ca[3], fmaf(REC_LO[3], ca[2], fmaf(REC_LO[5], ca[1], REC_LO[7] * ca[0])));
                y1 = fmaf(REC_HI[1], cd[3], fmaf(REC_HI[3], cd[2], fmaf(REC_HI[5], cd[1], fmaf(REC_HI[7], cd[0], y1))));
                float y2 = fmaf(REC_LO[0], ca[4], fmaf(REC_LO[2], ca[3], fmaf(REC_LO[4], ca[2], REC_LO[6] * ca[1])));
                y2 = fmaf(REC_HI[0], cd[4], fmaf(REC_HI[2], cd[3], fmaf(REC_HI[4], cd[2], fmaf(REC_HI[6], cd[1], y2))));
                float y3 = fmaf(REC_LO[1], ca[4], fmaf(REC_LO[3], ca[3], fmaf(REC_LO[5], ca[2], REC_LO[7] * ca[1])));
                y3 = fmaf(REC_HI[1], cd[4], fmaf(REC_HI[3], cd[3], fmaf(REC_HI[5], cd[2], fmaf(REC_HI[7], cd[1], y3))));
                orow[b] = make_float4(y0, y1, y2, y3);
            }
        }
    }
}

extern "C" void kernel_launch(void* const* d_in, const int* in_sizes, int n_in,
                              void* d_out, int out_size, void* d_ws, size_t ws_size,
                              hipStream_t stream) {
    const float* x = (const float*)d_in[0];
    const float* thr = (const float*)d_in[1];
    float* out = (float*)d_out;
    const int nrow = in_sizes[0] / NCOL;
    const int nblk = (nrow + RPB - 1) / RPB;
    hipLaunchKernelGGL(wavelet_kernel, dim3(nblk), dim3(NT), 0, stream, x, thr, out, nrow);
}

// Round 2
// 254.320 us; speedup vs baseline: 1.0748x; 1.0748x over previous
//
#include <hip/hip_runtime.h>

#define NCOL 1116
#define NLEV 7
#define NT 256
#define RPB 4        // rows per block, one wave each
#define ARENA 2048   // floats of LDS per row (8 KB)

static __device__ __forceinline__ float softf(float c, float t) {
    return copysignf(fmaxf(fabsf(c) - t, 0.0f), c);
}

__global__ __launch_bounds__(NT)
void wavelet_kernel(const float* __restrict__ x,
                    const float* __restrict__ thr_ptr,
                    float* __restrict__ out, int nrow) {
    constexpr float DEC_LO[8] = {-0.010597401784997278f,  0.032883011666982945f,
                                  0.030841381835986965f, -0.18703481171888114f,
                                 -0.02798376941698385f,   0.6308807679295904f,
                                  0.7148465705525415f,    0.23037781330885523f};
    constexpr float DEC_HI[8] = {-0.23037781330885523f,   0.7148465705525415f,
                                 -0.6308807679295904f,   -0.02798376941698385f,
                                  0.18703481171888114f,   0.030841381835986965f,
                                 -0.032883011666982945f, -0.010597401784997278f};
    constexpr float REC_LO[8] = { 0.23037781330885523f,   0.7148465705525415f,
                                  0.6308807679295904f,   -0.02798376941698385f,
                                 -0.18703481171888114f,   0.030841381835986965f,
                                  0.032883011666982945f, -0.010597401784997278f};
    constexpr float REC_HI[8] = {-0.010597401784997278f, -0.032883011666982945f,
                                  0.030841381835986965f,  0.18703481171888114f,
                                 -0.02798376941698385f,  -0.6308807679295904f,
                                  0.7148465705525415f,   -0.23037781330885523f};

    // approx lengths per level
    constexpr int alen[8] = {1116, 561, 284, 145, 76, 41, 24, 15};
    // detail segment offsets in dpool (all even, for float2-aligned reads)
    constexpr int doff[7] = {0, 562, 846, 992, 1068, 1110, 1134};

    __shared__ __align__(16) float SH[RPB * ARENA];

    const int lane = threadIdx.x & 63;
    const int wv   = threadIdx.x >> 6;
    const int row  = blockIdx.x * RPB + wv;
    if (row >= nrow) return;   // no block barriers anywhere -> safe

    const float thr = fmaxf(thr_ptr[0], 0.01f);

    float* const arena = SH + wv * ARENA;
    float* const dpool = arena;          // d0..d6 in [0,1150)
    float* const b8    = arena + 1156;   // B data; region [1150,1726): 6 front pads
    float* const c8    = arena + 1732;   // C data; region [1726,2048): 6 front pads

    // ---- forward level 0: windows straight from global x (L1-cached) ----
    {
        const float* xrow = x + (size_t)row * NCOL;
        #pragma unroll
        for (int k = 0; k < 9; ++k) {
            const int o = lane + (k << 6);
            if (o < 561) {
                float v[8];
                if (o >= 3 && o <= 557) {
                    const float2* p = (const float2*)(xrow + 2 * o - 6);
                    float2 q0 = p[0], q1 = p[1], q2 = p[2], q3 = p[3];
                    v[0] = q0.x; v[1] = q0.y; v[2] = q1.x; v[3] = q1.y;
                    v[4] = q2.x; v[5] = q2.y; v[6] = q3.x; v[7] = q3.y;
                } else {
                    #pragma unroll
                    for (int j = 0; j < 8; ++j) {
                        const int idx = 2 * o - 6 + j;
                        v[j] = (idx >= 0 && idx < NCOL) ? xrow[idx] : 0.0f;
                    }
                }
                float lo = 0.0f, hi = 0.0f;
                #pragma unroll
                for (int s = 0; s < 8; ++s) {
                    lo = fmaf(DEC_LO[s], v[7 - s], lo);
                    hi = fmaf(DEC_HI[s], v[7 - s], hi);
                }
                b8[o]    = lo;               // a1
                dpool[o] = softf(hi, thr);   // d0
            }
        }
        // zero pads of B: front 6, back 8
        if (lane < 14) { const int j = lane < 6 ? lane - 6 : 555 + lane; b8[j] = 0.0f; }
        __builtin_amdgcn_wave_barrier();
    }

    // ---- forward levels 1..6 (conflict-free stride-2 float2 reads) ----
    #pragma unroll
    for (int l = 1; l < NLEV; ++l) {
        const int nout = alen[l + 1];
        float* const cur = (l & 1) ? b8 : c8;
        float* const nxt = (l & 1) ? c8 : b8;
        float* const dp  = dpool + doff[l];
        const int K = (nout + 63) >> 6;
        #pragma unroll
        for (int k = 0; k < K; ++k) {
            const int o = lane + (k << 6);
            if (o < nout) {
                const float2* p = (const float2*)(cur + 2 * o - 6);
                float2 q0 = p[0], q1 = p[1], q2 = p[2], q3 = p[3];
                float v[8];
                v[0] = q0.x; v[1] = q0.y; v[2] = q1.x; v[3] = q1.y;
                v[4] = q2.x; v[5] = q2.y; v[6] = q3.x; v[7] = q3.y;
                float lo = 0.0f, hi = 0.0f;
                #pragma unroll
                for (int s = 0; s < 8; ++s) {
                    lo = fmaf(DEC_LO[s], v[7 - s], lo);
                    hi = fmaf(DEC_HI[s], v[7 - s], hi);
                }
                nxt[o] = (l == NLEV - 1) ? softf(lo, thr) : lo;  // a7 threshold fused
                dp[o]  = softf(hi, thr);
            }
        }
        if (l < NLEV - 1 && lane < 14) {
            const int j = lane < 6 ? lane - 6 : nout + lane - 6;  // front 6 / back 8
            nxt[j] = 0.0f;
        }
        __builtin_amdgcn_wave_barrier();
    }

    // ---- inverse levels 6..1 (2 pairs/lane, float4 stores) ----
    #pragma unroll
    for (int l = NLEV - 1; l >= 1; --l) {
        const int M = alen[l + 1];
        const int npair = M - 3;
        const float* const cur = (l & 1) ? c8 : b8;   // a7 starts in B (l=6 even)
        float* const nxt       = (l & 1) ? b8 : c8;
        const float* const dp  = dpool + doff[l];
        const int KI = (((npair + 1) >> 1) + 63) >> 6;
        #pragma unroll
        for (int kk = 0; kk < KI; ++kk) {
            const int m = (lane + (kk << 6)) << 1;
            if (m < npair) {
                float ca[5], cd[5];
                #pragma unroll
                for (int j = 0; j < 5; ++j) { ca[j] = cur[m + j]; cd[j] = dp[m + j]; }
                float y0 = fmaf(REC_LO[0], ca[3], fmaf(REC_LO[2], ca[2], fmaf(REC_LO[4], ca[1], REC_LO[6] * ca[0])));
                y0 = fmaf(REC_HI[0], cd[3], fmaf(REC_HI[2], cd[2], fmaf(REC_HI[4], cd[1], fmaf(REC_HI[6], cd[0], y0))));
                float y1 = fmaf(REC_LO[1], ca[3], fmaf(REC_LO[3], ca[2], fmaf(REC_LO[5], ca[1], REC_LO[7] * ca[0])));
                y1 = fmaf(REC_HI[1], cd[3], fmaf(REC_HI[3], cd[2], fmaf(REC_HI[5], cd[1], fmaf(REC_HI[7], cd[0], y1))));
                if (m + 1 < npair) {
                    float y2 = fmaf(REC_LO[0], ca[4], fmaf(REC_LO[2], ca[3], fmaf(REC_LO[4], ca[2], REC_LO[6] * ca[1])));
                    y2 = fmaf(REC_HI[0], cd[4], fmaf(REC_HI[2], cd[3], fmaf(REC_HI[4], cd[2], fmaf(REC_HI[6], cd[1], y2))));
                    float y3 = fmaf(REC_LO[1], ca[4], fmaf(REC_LO[3], ca[3], fmaf(REC_LO[5], ca[2], REC_LO[7] * ca[1])));
                    y3 = fmaf(REC_HI[1], cd[4], fmaf(REC_HI[3], cd[3], fmaf(REC_HI[5], cd[2], fmaf(REC_HI[7], cd[1], y3))));
                    *(float4*)(nxt + 2 * m) = make_float4(y0, y1, y2, y3);
                } else {
                    nxt[2 * m]     = y0;
                    nxt[2 * m + 1] = y1;
                }
            }
        }
        __builtin_amdgcn_wave_barrier();
    }

    // ---- inverse level 0: read B + d0, write global float4 ----
    {
        const float* const cur = b8;     // a1' (562 floats)
        const float* const dp  = dpool;  // d0
        float4* orow = (float4*)(out + (size_t)row * NCOL);
        #pragma unroll
        for (int kk = 0; kk < 5; ++kk) {
            const int bq = lane + (kk << 6);
            const int m = bq << 1;
            if (m < 558) {   // 558 even -> every active lane writes a full quad
                float ca[5], cd[5];
                #pragma unroll
                for (int j = 0; j < 5; ++j) { ca[j] = cur[m + j]; cd[j] = dp[m + j]; }
                float y0 = fmaf(REC_LO[0], ca[3], fmaf(REC_LO[2], ca[2], fmaf(REC_LO[4], ca[1], REC_LO[6] * ca[0])));
                y0 = fmaf(REC_HI[0], cd[3], fmaf(REC_HI[2], cd[2], fmaf(REC_HI[4], cd[1], fmaf(REC_HI[6], cd[0], y0))));
                float y1 = fmaf(REC_LO[1], ca[3], fmaf(REC_LO[3], ca[2], fmaf(REC_LO[5], ca[1], REC_LO[7] * ca[0])));
                y1 = fmaf(REC_HI[1], cd[3], fmaf(REC_HI[3], cd[2], fmaf(REC_HI[5], cd[1], fmaf(REC_HI[7], cd[0], y1))));
                float y2 = fmaf(REC_LO[0], ca[4], fmaf(REC_LO[2], ca[3], fmaf(REC_LO[4], ca[2], REC_LO[6] * ca[1])));
                y2 = fmaf(REC_HI[0], cd[4], fmaf(REC_HI[2], cd[3], fmaf(REC_HI[4], cd[2], fmaf(REC_HI[6], cd[1], y2))));
                float y3 = fmaf(REC_LO[1], ca[4], fmaf(REC_LO[3], ca[3], fmaf(REC_LO[5], ca[2], REC_LO[7] * ca[1])));
                y3 = fmaf(REC_HI[1], cd[4], fmaf(REC_HI[3], cd[3], fmaf(REC_HI[5], cd[2], fmaf(REC_HI[7], cd[1], y3))));
                orow[bq] = make_float4(y0, y1, y2, y3);
            }
        }
    }
}

extern "C" void kernel_launch(void* const* d_in, const int* in_sizes, int n_in,
                              void* d_out, int out_size, void* d_ws, size_t ws_size,
                              hipStream_t stream) {
    const float* x = (const float*)d_in[0];
    const float* thr = (const float*)d_in[1];
    float* out = (float*)d_out;
    const int nrow = in_sizes[0] / NCOL;
    const int nblk = (nrow + RPB - 1) / RPB;
    hipLaunchKernelGGL(wavelet_kernel, dim3(nblk), dim3(NT), 0, stream, x, thr, out, nrow);
}